// Round 19
// baseline (219.010 us; speedup 1.0000x reference)
//
#include <hip/hip_runtime.h>
#include <math.h>

// ---------------- problem constants ----------------
#define PP    25
#define CCH   640
#define NCOL  5000
#define SCALE_INV 0.17677669529663687f   // 1/sqrt(32)

// ---------------- workspace float offsets (r12 layout) ----------------
#define XTB_OFF   0L         // bf16 [5000][640]
#define WB_OFF    1600000L   // bf16 [3][640][640]
#define PROJB_OFF 2214400L   // bf16 [3][5000][640], stored [col][o]
#define MMD_OFF   7014400L   // [750]
#define ONES_OFF  7015168L   // bf16 [6][64]: row250=1.0, 251-255=0
#define FEAT_OFF  7015360L   // bf16, head-blocked [way][20][250][32]
#define FEAT_PER_WAY_US 160000L
#define FEAT_PER_PAIR_US 800000L

typedef __attribute__((ext_vector_type(8)))  short          s16x8;
typedef __attribute__((ext_vector_type(8)))  unsigned short u16x8;
typedef __attribute__((ext_vector_type(4)))  unsigned short u16x4;
typedef __attribute__((ext_vector_type(16))) float          f32x16;

typedef __attribute__((address_space(1))) const unsigned int glb_u32;
typedef __attribute__((address_space(3))) unsigned int       lds_u32;

__device__ inline unsigned short f2bf(float x) {
  unsigned u = __float_as_uint(x);
  unsigned r = u + 0x7fff + ((u >> 16) & 1);   // RNE
  return (unsigned short)(r >> 16);
}
__device__ inline float bf2f(unsigned short b) {
  return __uint_as_float(((unsigned)b) << 16);
}
__device__ inline unsigned cvtpk(float lo, float hi) {
  unsigned r;
  asm("v_cvt_pk_bf16_f32 %0, %1, %2" : "=v"(r) : "v"(lo), "v"(hi));
  return r;
}
// v_permlane32_swap_b32: vdst lanes 0-31 <-> src lanes 32-63 (both modified)
__device__ inline void plswap(unsigned &a, unsigned &b) {
  asm volatile("v_permlane32_swap_b32 %0, %1" : "+v"(a), "+v"(b));
}

// upper-triangle tile LUT: wave w owns tiles (TI[w], TJ0[w]+a), a < NT[w]
__device__ const char gTI[15]  = {0,0,0,1,1,1,2,2,3,3,4,4,5,6,7};
__device__ const char gTJ0[15] = {0,3,6,1,4,7,2,5,3,6,4,7,5,6,7};
__device__ const char gNT[15]  = {3,3,2,3,3,1,3,3,3,2,3,1,3,2,1};

// =====================================================================
// Kernel T: build XTB bf16 [col][c]
// =====================================================================
__global__ __launch_bounds__(256) void t_kernel(const float* __restrict__ sup,
                                                const float* __restrict__ qry,
                                                unsigned short* __restrict__ XTB) {
  __shared__ float lds[16000];
  int item = blockIdx.x;
  const float* src = (item < 50) ? (sup + item * 16000) : (qry + (item - 50) * 16000);
  int tid = threadIdx.x;
  for (int e = tid * 4; e < 16000; e += 1024)
    *(float4*)&lds[e] = *(const float4*)&src[e];
  __syncthreads();
  int ibase = item * PP;
  for (int e = tid * 4; e < 16000; e += 1024) {
    int p = e / CCH, c = e - p * CCH;
    u16x4 b;
    b.x = f2bf(lds[(c + 0) * PP + p]);
    b.y = f2bf(lds[(c + 1) * PP + p]);
    b.z = f2bf(lds[(c + 2) * PP + p]);
    b.w = f2bf(lds[(c + 3) * PP + p]);
    *(u16x4*)&XTB[(long)(ibase + p) * CCH + c] = b;
  }
}

// =====================================================================
// Kernel W: Wq/Wk/Wv fp32 -> bf16; block 0 also inits the ones region
// =====================================================================
__global__ __launch_bounds__(256) void w_kernel(const float* __restrict__ Wq,
                                                const float* __restrict__ Wk,
                                                const float* __restrict__ Wv,
                                                unsigned short* __restrict__ WB,
                                                unsigned short* __restrict__ ones) {
  if (blockIdx.x == 0 && threadIdx.x < 384)
    ones[threadIdx.x] = (threadIdx.x < 64) ? (unsigned short)0x3F80 : (unsigned short)0;
  long base = ((long)blockIdx.x * 256 + threadIdx.x) * 8;
  int m = (int)(base / 409600L);
  long off = base - (long)m * 409600L;
  const float* W = (m == 0) ? Wq : ((m == 1) ? Wk : Wv);
  float4 a = *(const float4*)&W[off];
  float4 c = *(const float4*)&W[off + 4];
  u16x8 v;
  v[0] = f2bf(a.x); v[1] = f2bf(a.y); v[2] = f2bf(a.z); v[3] = f2bf(a.w);
  v[4] = f2bf(c.x); v[5] = f2bf(c.y); v[6] = f2bf(c.z); v[7] = f2bf(c.w);
  *(u16x8*)&WB[base] = v;
}

// =====================================================================
// Kernel A: MFMA bf16 projections -> bf16 projB [m][col][o]  (r12 form)
// =====================================================================
__global__ __launch_bounds__(512) void proj_kernel(const unsigned short* __restrict__ WB,
                                                   const unsigned short* __restrict__ XTB,
                                                   unsigned short* __restrict__ proj) {
  __shared__ __align__(16) unsigned short At[128 * 64];
  __shared__ __align__(16) unsigned short Bt[128 * 64];
  int m = blockIdx.z;
  int ctile = blockIdx.x * 128, otile = blockIdx.y * 128;
  const unsigned short* Wsrc = WB + (long)m * 409600L;
  unsigned short* out = proj + (long)m * NCOL * CCH;
  int tid = threadIdx.x;
  int w = tid >> 6, lane = tid & 63;
  int wr = w >> 2, wc = w & 3;
  int lr = lane & 31, ksel = lane >> 5;
  int sr = tid >> 2, sg = (tid & 3) * 2;

  f32x16 acc[2];
#pragma unroll
  for (int a = 0; a < 2; a++)
#pragma unroll
    for (int e = 0; e < 16; e++) acc[a][e] = 0.f;

  int bcol = ctile + sr;
  const unsigned short* asrc = Wsrc + (long)(otile + sr) * CCH + sg * 8;
  const unsigned short* bsrc = XTB + (long)bcol * CCH + sg * 8;

  u16x8 pa[2], pb[2];
#pragma unroll
  for (int gi = 0; gi < 2; gi++) {
    pa[gi] = *(const u16x8*)&asrc[gi * 8];
    if (bcol < NCOL) pb[gi] = *(const u16x8*)&bsrc[gi * 8];
    else { u16x8 z; for (int e = 0; e < 8; e++) z[e] = 0; pb[gi] = z; }
  }

  for (int kc = 0; kc < 10; kc++) {
    __syncthreads();
#pragma unroll
    for (int gi = 0; gi < 2; gi++) {
      int g = sg + gi;
      *(u16x8*)&At[sr * 64 + ((g ^ (sr & 7)) << 3)] = pa[gi];
      *(u16x8*)&Bt[sr * 64 + ((g ^ (sr & 7)) << 3)] = pb[gi];
    }
    if (kc < 9) {
      const unsigned short* an = asrc + (kc + 1) * 64;
      const unsigned short* bn = bsrc + (kc + 1) * 64;
#pragma unroll
      for (int gi = 0; gi < 2; gi++) {
        pa[gi] = *(const u16x8*)&an[gi * 8];
        if (bcol < NCOL) pb[gi] = *(const u16x8*)&bn[gi * 8];
      }
    }
    __syncthreads();
#pragma unroll
    for (int ks = 0; ks < 4; ks++) {
      int gk = ks * 2 + ksel;
      s16x8 bf1;
      {
        int R = wc * 32 + lr;
        bf1 = *(const s16x8*)&Bt[R * 64 + ((gk ^ (R & 7)) << 3)];
      }
#pragma unroll
      for (int a = 0; a < 2; a++) {
        int R = (wr + 2 * a) * 32 + lr;
        s16x8 af = *(const s16x8*)&At[R * 64 + ((gk ^ (R & 7)) << 3)];
        acc[a] = __builtin_amdgcn_mfma_f32_32x32x16_bf16(af, bf1, acc[a], 0, 0, 0);
      }
    }
  }

  int col = ctile + wc * 32 + lr;
  if (col < NCOL) {
#pragma unroll
    for (int a = 0; a < 2; a++) {
      int obase = otile + (wr + 2 * a) * 32 + 4 * ksel;
#pragma unroll
      for (int g2 = 0; g2 < 4; g2++) {
        u16x4 v;
        v.x = f2bf(acc[a][g2 * 4 + 0]);
        v.y = f2bf(acc[a][g2 * 4 + 1]);
        v.z = f2bf(acc[a][g2 * 4 + 2]);
        v.w = f2bf(acc[a][g2 * 4 + 3]);
        *(u16x4*)&out[(long)col * CCH + obase + g2 * 8] = v;
      }
    }
  }
}

// =====================================================================
// Kernel B: MFMA attention, templated on SIDE (r17-verified)
// =====================================================================
template<int SIDE>
__global__ __launch_bounds__(256) void attn_kernel(const unsigned short* __restrict__ proj,
                                                   const unsigned short* __restrict__ XTB,
                                                   unsigned short* __restrict__ feat,
                                                   int chunk_start) {
  int tid = threadIdx.x, wid = tid >> 6, lane = tid & 63;
  int lr = lane & 31, hf = lane >> 5;
  int rclamp = lr > 24 ? 24 : lr;
  int bid = blockIdx.x;
  int pw = bid / 5, grp = bid - pw * 5;
  int head = grp * 4 + wid;           // 0..19
  int lpi = pw / 5, way = pw - lpi * 5;
  int pair = chunk_start + lpi;
  int b = pair / 75;
  int qitem = 50 + pair;
  int qcol = qitem * PP;
  int sitem0 = b * 25 + way * 5;
  int ho = head * 32;
  const unsigned short* Qp = proj;
  const unsigned short* Kp = proj + (long)NCOL * CCH;
  const unsigned short* Vp = proj + 2L * NCOL * CCH;
  unsigned short* fb = feat + (long)pw * FEAT_PER_WAY_US + head * 250 * 32;

  auto ldfrag = [&](const unsigned short* src, int col0, int ks) -> s16x8 {
    return *(const s16x8*)&src[(long)(col0 + rclamp) * CCH + ho + ks * 16 + hf * 8];
  };
  auto ldvfrag = [&](int col0, int ks) -> s16x8 {
    const unsigned short* base = Vp + (long)(col0 + ks * 16 + hf * 8) * CCH + ho + lr;
    s16x8 f;
#pragma unroll
    for (int j = 0; j < 8; j++) f[j] = (short)base[(long)j * CCH];
    return f;
  };

  s16x8 fA0, fA1, fB0, fB1, fV0, fV1;
  float scv[16];
  if (SIDE == 0) {               // sbq: Q = query item fixed
    fB0 = ldfrag(Qp, qcol, 0); fB1 = ldfrag(Qp, qcol, 1);
  } else {                       // qbs: K/V = query item fixed; shortcut fixed too
    fA0 = ldfrag(Kp, qcol, 0); fA1 = ldfrag(Kp, qcol, 1);
    fV0 = ldvfrag(qcol, 0);    fV1 = ldvfrag(qcol, 1);
#pragma unroll
    for (int rg = 0; rg < 16; rg++) {
      int q = (rg & 3) + 8 * (rg >> 2) + 4 * hf;
      int qc = q > 24 ? 24 : q;
      scv[rg] = bf2f(XTB[(long)(qcol + qc) * CCH + ho + lr]);
    }
  }

#pragma unroll
  for (int shot = 0; shot < 5; shot++) {
    int scol = (sitem0 + shot) * PP;
    s16x8 A0, A1, B0, B1, V0, V1;
    if (SIDE == 0) {
      A0 = ldfrag(Kp, scol, 0); A1 = ldfrag(Kp, scol, 1);
      B0 = fB0; B1 = fB1;
      V0 = ldvfrag(scol, 0);    V1 = ldvfrag(scol, 1);
    } else {
      A0 = fA0; A1 = fA1;
      B0 = ldfrag(Qp, scol, 0); B1 = ldfrag(Qp, scol, 1);
      V0 = fV0; V1 = fV1;
    }
    // S^T = K·Q^T : D[m][q], q = lr
    f32x16 s;
#pragma unroll
    for (int e = 0; e < 16; e++) s[e] = 0.f;
    s = __builtin_amdgcn_mfma_f32_32x32x16_bf16(A0, B0, s, 0, 0, 0);
    s = __builtin_amdgcn_mfma_f32_32x32x16_bf16(A1, B1, s, 0, 0, 0);
    // softmax: tree max (unmasked; m>=25 replicates valid row 24)
    float t8[8];
#pragma unroll
    for (int i = 0; i < 8; i++) t8[i] = fmaxf(s[i], s[i + 8]);
#pragma unroll
    for (int i = 0; i < 4; i++) t8[i] = fmaxf(t8[i], t8[i + 4]);
    float mx = fmaxf(fmaxf(t8[0], t8[1]), fmaxf(t8[2], t8[3]));
    mx = fmaxf(mx, __shfl_xor(mx, 32));
    float pv[16];
#pragma unroll
    for (int rg = 0; rg < 16; rg++) pv[rg] = __expf((s[rg] - mx) * SCALE_INV);
    pv[13] = 0.f; pv[14] = 0.f; pv[15] = 0.f;   // m=25,26,27 / 29,30,31
    if (hf) pv[12] = 0.f;                        // m=28
    float s8[8];
#pragma unroll
    for (int i = 0; i < 8; i++) s8[i] = pv[i] + pv[i + 8];
#pragma unroll
    for (int i = 0; i < 4; i++) s8[i] = s8[i] + s8[i + 4];
    float sum = (s8[0] + s8[1]) + (s8[2] + s8[3]);
    sum += __shfl_xor(sum, 32);
    float rinv = 1.f / sum;
    // P A-frags: cvt_pk then permlane32_swap half-exchange
    union { unsigned u[4]; s16x8 v; } P0u, P1u;
    {
      unsigned a0 = cvtpk(pv[0], pv[1]),  a1 = cvtpk(pv[2], pv[3]);
      unsigned a2 = cvtpk(pv[4], pv[5]),  a3 = cvtpk(pv[6], pv[7]);
      plswap(a2, a0);
      plswap(a3, a1);
      P0u.u[0] = a0; P0u.u[1] = a1; P0u.u[2] = a2; P0u.u[3] = a3;
      unsigned b0 = cvtpk(pv[8], pv[9]),   b1 = cvtpk(pv[10], pv[11]);
      unsigned b2 = cvtpk(pv[12], pv[13]), b3 = cvtpk(pv[14], pv[15]);
      plswap(b2, b0);
      plswap(b3, b1);
      P1u.u[0] = b0; P1u.u[1] = b1; P1u.u[2] = b2; P1u.u[3] = b3;
    }
    // O = P·V (unnormalized)
    f32x16 o;
#pragma unroll
    for (int e = 0; e < 16; e++) o[e] = 0.f;
    o = __builtin_amdgcn_mfma_f32_32x32x16_bf16(P0u.v, V0, o, 0, 0, 0);
    o = __builtin_amdgcn_mfma_f32_32x32x16_bf16(P1u.v, V1, o, 0, 0, 0);
    // epilogue: o*rinv + shortcut, paired cvt_pk, bf16 store
    unsigned short* frow = fb + (long)((SIDE ? 125 : 0) + shot * 25) * 32;
    const unsigned short* scb = XTB + (long)(scol + 4 * hf) * CCH + ho + lr;
#pragma unroll
    for (int i = 0; i < 8; i++) {
      int rg0 = 2 * i, rg1 = rg0 + 1;
      int qoff = (rg0 & 3) + 8 * (rg0 >> 2);
      int q0 = qoff + 4 * hf, q1 = q0 + 1;
      float sc0, sc1;
      if (SIDE) { sc0 = scv[rg0]; sc1 = scv[rg1]; }
      else {
        sc0 = bf2f(scb[(long)qoff * CCH]);
        sc1 = bf2f(scb[(long)(qoff + 1) * CCH]);
      }
      unsigned u = cvtpk(fmaf(o[rg0], rinv, sc0), fmaf(o[rg1], rinv, sc1));
      if (q0 < 25) frow[q0 * 32 + lr] = (unsigned short)u;
      if (q1 < 25) frow[q1 * 32 + lr] = (unsigned short)(u >> 16);
    }
  }
}

// =====================================================================
// Kernel C: MFMA bf16 Gram, symmetric row-grouped triangle.
// 1024 thr / 16 waves; wave w owns tiles (gTI[w], gTJ0[w]+a), a<gNT[w]
// (36 upper-triangle tiles of the 8x8 grid; wave 15 idles compute).
// Per ks: 1 af + nt bf reads, nt MFMAs. Weight 2 for ti<tj tiles.
// Staging / swizzle / dbuf / ones-row harvest = r17-verified.
// =====================================================================
__global__ __launch_bounds__(1024) void gram_kernel(const unsigned short* __restrict__ feat,
                                                    const unsigned short* __restrict__ ones,
                                                    float* __restrict__ mmd,
                                                    int chunk_start) {
  __shared__ __align__(16) unsigned short tile[2][16384];
  __shared__ float sums[256], nrmsq[256], meanv[256], nrmv[256];
  __shared__ float red[48];
  int bid = blockIdx.x;
  const unsigned short* fb = feat + (long)bid * FEAT_PER_WAY_US;
  int tid = threadIdx.x;
  int w = tid >> 6, lane = tid & 63;
  int lr = lane & 31, ksel = lane >> 5;

  int ti = 0, tj0 = 0, nt = 0;
  if (w < 15) { ti = gTI[w]; tj0 = gTJ0[w]; nt = gNT[w]; }

  const unsigned short* srcp[2];
  long stepv[2];
#pragma unroll
  for (int i = 0; i < 2; i++) {
    int s = (w * 2 + i) * 64 + lane;
    int row = s >> 3, gs = s & 7, g = gs ^ (row & 7);
    if (row < 250) {
      srcp[i] = fb + (long)((g >> 2) * 250 + row) * 32 + (g & 3) * 8;
      stepv[i] = 16000;
    } else {
      srcp[i] = ones + (row - 250) * 64 + g * 8;
      stepv[i] = 0;
    }
  }

  f32x16 acc[3];
#pragma unroll
  for (int a = 0; a < 3; a++)
#pragma unroll
    for (int e = 0; e < 16; e++) acc[a][e] = 0.f;

#pragma unroll
  for (int i = 0; i < 2; i++)
    __builtin_amdgcn_global_load_lds((glb_u32*)srcp[i],
                                     (lds_u32*)&tile[0][(w * 2 + i) * 512], 16, 0, 0);
  __syncthreads();

  for (int kc = 0; kc < 10; kc++) {
    int cur = kc & 1;
    if (kc < 9) {
#pragma unroll
      for (int i = 0; i < 2; i++)
        __builtin_amdgcn_global_load_lds((glb_u32*)(srcp[i] + (long)(kc + 1) * stepv[i]),
                                         (lds_u32*)&tile[cur ^ 1][(w * 2 + i) * 512], 16, 0, 0);
    }
    const unsigned short* tb = tile[cur];
    if (w < 15) {
#pragma unroll
      for (int ks = 0; ks < 4; ks++) {
        int gk = ks * 2 + ksel;
        int Ra = ti * 32 + lr;
        s16x8 af = *(const s16x8*)&tb[Ra * 64 + ((gk ^ (Ra & 7)) << 3)];
#pragma unroll
        for (int a = 0; a < 3; a++) {
          if (a < nt) {
            int Rb = (tj0 + a) * 32 + lr;
            s16x8 bf1 = *(const s16x8*)&tb[Rb * 64 + ((gk ^ (Rb & 7)) << 3)];
            acc[a] = __builtin_amdgcn_mfma_f32_32x32x16_bf16(af, bf1, acc[a], 0, 0, 0);
          }
        }
      }
    }
    __syncthreads();
  }

  // ---- harvest row sums (col 250, tiles (ti,7)) and squared norms (diag) ----
  if (w < 15) {
#pragma unroll
    for (int a = 0; a < 3; a++) {
      if (a < nt) {
        int tj = tj0 + a;
        int col = tj * 32 + lr;
        if (col == 250) {
#pragma unroll
          for (int rg = 0; rg < 16; rg++) {
            int row = ti * 32 + (rg & 3) + 8 * (rg >> 2) + 4 * ksel;
            if (row < 250) sums[row] = acc[a][rg];
          }
        }
        if (ti == tj) {
#pragma unroll
          for (int rg = 0; rg < 16; rg++) {
            int row = ti * 32 + (rg & 3) + 8 * (rg >> 2) + 4 * ksel;
            if (row == col && row < 250) nrmsq[row] = acc[a][rg];
          }
        }
      }
    }
  }
  __syncthreads();
  if (tid < 250) {
    float s0 = sums[tid];
    float m = s0 * (1.f / 640.f);
    meanv[tid] = m;
    nrmv[tid] = nrmsq[tid] - s0 * m;
  }
  __syncthreads();

  // ---- epilogue: d2 -> 5-term kernel; weight 2 for ti<tj ----
  float s_ss = 0.f, s_qq = 0.f, s_x = 0.f;
  if (w < 15) {
#pragma unroll
    for (int a = 0; a < 3; a++) {
      if (a < nt) {
        int tj = tj0 + a;
        float w2 = (ti < tj) ? 2.f : 1.f;
        int col = tj * 32 + lr;
#pragma unroll
        for (int rg = 0; rg < 16; rg++) {
          int row = ti * 32 + (rg & 3) + 8 * (rg >> 2) + 4 * ksel;
          if (row < 250 && col < 250) {
            float d2 = nrmv[row] + nrmv[col] - 2.f * acc[a][rg]
                     + 1280.f * meanv[row] * meanv[col];
            d2 = fmaxf(d2, 0.f);
            float e = __expf(-0.125f * d2);
            float e2 = e * e, e4 = e2 * e2, e8 = e4 * e4, e16 = e8 * e8;
            float kv = w2 * (e + e2 + e4 + e8 + e16);
            bool rs = row < 125, cs = col < 125;
            if (rs && cs)        { if (row != col) s_ss += kv; }
            else if (!rs && !cs) { if (row != col) s_qq += kv; }
            else                 s_x += kv;   // Kqs + Ksq = 2*tot(Kqs)
          }
        }
      }
    }
  }
#pragma unroll
  for (int off = 32; off; off >>= 1) {
    s_ss += __shfl_xor(s_ss, off);
    s_qq += __shfl_xor(s_qq, off);
    s_x  += __shfl_xor(s_x, off);
  }
  if (lane == 0) { red[w * 3] = s_ss; red[w * 3 + 1] = s_qq; red[w * 3 + 2] = s_x; }
  __syncthreads();
  if (tid == 0) {
    float a = 0.f, b2 = 0.f, c = 0.f;
    for (int i = 0; i < 16; i++) { a += red[i * 3]; b2 += red[i * 3 + 1]; c += red[i * 3 + 2]; }
    mmd[(long)chunk_start * 5 + bid] = a * (1.f / 15500.f) + b2 * (1.f / 15500.f) - c * (1.f / 15625.f);
  }
}

// =====================================================================
// Kernel D: log-softmax + NLL mean
// =====================================================================
__global__ __launch_bounds__(256) void loss_kernel(const float* __restrict__ mmd,
                                                   const int* __restrict__ qy,
                                                   float* __restrict__ out) {
  __shared__ float red[256];
  int tid = threadIdx.x;
  float val = 0.f;
  if (tid < 150) {
    float l[5];
    float mx = -1e30f;
#pragma unroll
    for (int w = 0; w < 5; w++) {
      l[w] = -mmd[tid * 5 + w] * (1.0f / 12.5f);
      mx = fmaxf(mx, l[w]);
    }
    float sum = 0.f;
#pragma unroll
    for (int w = 0; w < 5; w++) sum += __expf(l[w] - mx);
    float lse = mx + logf(sum);
    int y = qy[tid];
    val = -(l[y] - lse);
  }
  red[tid] = val;
  __syncthreads();
  for (int s = 128; s > 0; s >>= 1) {
    if (tid < s) red[tid] += red[tid + s];
    __syncthreads();
  }
  if (tid == 0) out[0] = red[0] * (1.0f / 150.0f);
}

// =====================================================================
extern "C" void kernel_launch(void* const* d_in, const int* in_sizes, int n_in,
                              void* d_out, int out_size, void* d_ws, size_t ws_size,
                              hipStream_t stream) {
  (void)in_sizes; (void)n_in; (void)out_size;
  const float* sup = (const float*)d_in[0];
  const float* qry = (const float*)d_in[2];
  const int* qy = (const int*)d_in[3];
  const float* Wq = (const float*)d_in[4];
  const float* Wk = (const float*)d_in[5];
  const float* Wv = (const float*)d_in[6];
  float* ws = (float*)d_ws;
  unsigned short* XTB = (unsigned short*)(ws + XTB_OFF);
  unsigned short* WB = (unsigned short*)(ws + WB_OFF);
  unsigned short* projB = (unsigned short*)(ws + PROJB_OFF);
  float* mmd = ws + MMD_OFF;
  unsigned short* ones = (unsigned short*)(ws + ONES_OFF);
  unsigned short* feat = (unsigned short*)(ws + FEAT_OFF);
  float* out = (float*)d_out;

  long wsf = (long)(ws_size / 4);
  long avail_us = (wsf - FEAT_OFF) * 2;
  long chunkL = avail_us / FEAT_PER_PAIR_US;
  int chunk = (chunkL > 150) ? 150 : (chunkL < 1 ? 1 : (int)chunkL);

  hipLaunchKernelGGL(t_kernel, dim3(200), dim3(256), 0, stream, sup, qry, XTB);
  hipLaunchKernelGGL(w_kernel, dim3(600), dim3(256), 0, stream, Wq, Wk, Wv, WB, ones);
  hipLaunchKernelGGL(proj_kernel, dim3(40, 5, 3), dim3(512), 0, stream, WB, XTB, projB);
  for (int c0 = 0; c0 < 150; c0 += chunk) {
    int cp = (150 - c0 < chunk) ? (150 - c0) : chunk;
    hipLaunchKernelGGL((attn_kernel<0>), dim3(cp * 25), dim3(256), 0, stream, projB, XTB, feat, c0);
    hipLaunchKernelGGL((attn_kernel<1>), dim3(cp * 25), dim3(256), 0, stream, projB, XTB, feat, c0);
    hipLaunchKernelGGL(gram_kernel, dim3(cp * 5), dim3(1024), 0, stream, feat, ones, mmd, c0);
  }
  hipLaunchKernelGGL(loss_kernel, dim3(1), dim3(256), 0, stream, mmd, qy, out);
}

// Round 20
// 216.425 us; speedup vs baseline: 1.0119x; 1.0119x over previous
//
#include <hip/hip_runtime.h>
#include <math.h>

// ---------------- problem constants ----------------
#define PP    25
#define CCH   640
#define NCOL  5000
#define SCALE_INV 0.17677669529663687f   // 1/sqrt(32)

// ---------------- workspace float offsets (r12 layout) ----------------
#define XTB_OFF   0L         // bf16 [5000][640]
#define WB_OFF    1600000L   // bf16 [3][640][640]
#define PROJB_OFF 2214400L   // bf16 [3][5000][640], stored [col][o]
#define MMD_OFF   7014400L   // [750]
#define ONES_OFF  7015168L   // bf16 [6][64]: row250=1.0, 251-255=0
#define FEAT_OFF  7015360L   // bf16, head-blocked [way][20][250][32]
#define FEAT_PER_WAY_US 160000L
#define FEAT_PER_PAIR_US 800000L

typedef __attribute__((ext_vector_type(8)))  short          s16x8;
typedef __attribute__((ext_vector_type(8)))  unsigned short u16x8;
typedef __attribute__((ext_vector_type(4)))  unsigned short u16x4;
typedef __attribute__((ext_vector_type(16))) float          f32x16;

typedef __attribute__((address_space(1))) const unsigned int glb_u32;
typedef __attribute__((address_space(3))) unsigned int       lds_u32;

__device__ inline unsigned short f2bf(float x) {
  unsigned u = __float_as_uint(x);
  unsigned r = u + 0x7fff + ((u >> 16) & 1);   // RNE
  return (unsigned short)(r >> 16);
}
__device__ inline float bf2f(unsigned short b) {
  return __uint_as_float(((unsigned)b) << 16);
}
__device__ inline unsigned cvtpk(float lo, float hi) {
  unsigned r;
  asm("v_cvt_pk_bf16_f32 %0, %1, %2" : "=v"(r) : "v"(lo), "v"(hi));
  return r;
}
// v_permlane32_swap_b32: vdst lanes 0-31 <-> src lanes 32-63 (both modified)
__device__ inline void plswap(unsigned &a, unsigned &b) {
  asm volatile("v_permlane32_swap_b32 %0, %1" : "+v"(a), "+v"(b));
}

// =====================================================================
// Kernel T: build XTB bf16 [col][c]
// =====================================================================
__global__ __launch_bounds__(256) void t_kernel(const float* __restrict__ sup,
                                                const float* __restrict__ qry,
                                                unsigned short* __restrict__ XTB) {
  __shared__ float lds[16000];
  int item = blockIdx.x;
  const float* src = (item < 50) ? (sup + item * 16000) : (qry + (item - 50) * 16000);
  int tid = threadIdx.x;
  for (int e = tid * 4; e < 16000; e += 1024)
    *(float4*)&lds[e] = *(const float4*)&src[e];
  __syncthreads();
  int ibase = item * PP;
  for (int e = tid * 4; e < 16000; e += 1024) {
    int p = e / CCH, c = e - p * CCH;
    u16x4 b;
    b.x = f2bf(lds[(c + 0) * PP + p]);
    b.y = f2bf(lds[(c + 1) * PP + p]);
    b.z = f2bf(lds[(c + 2) * PP + p]);
    b.w = f2bf(lds[(c + 3) * PP + p]);
    *(u16x4*)&XTB[(long)(ibase + p) * CCH + c] = b;
  }
}

// =====================================================================
// Kernel W: Wq/Wk/Wv fp32 -> bf16; block 0 also inits the ones region
// =====================================================================
__global__ __launch_bounds__(256) void w_kernel(const float* __restrict__ Wq,
                                                const float* __restrict__ Wk,
                                                const float* __restrict__ Wv,
                                                unsigned short* __restrict__ WB,
                                                unsigned short* __restrict__ ones) {
  if (blockIdx.x == 0 && threadIdx.x < 384)
    ones[threadIdx.x] = (threadIdx.x < 64) ? (unsigned short)0x3F80 : (unsigned short)0;
  long base = ((long)blockIdx.x * 256 + threadIdx.x) * 8;
  int m = (int)(base / 409600L);
  long off = base - (long)m * 409600L;
  const float* W = (m == 0) ? Wq : ((m == 1) ? Wk : Wv);
  float4 a = *(const float4*)&W[off];
  float4 c = *(const float4*)&W[off + 4];
  u16x8 v;
  v[0] = f2bf(a.x); v[1] = f2bf(a.y); v[2] = f2bf(a.z); v[3] = f2bf(a.w);
  v[4] = f2bf(c.x); v[5] = f2bf(c.y); v[6] = f2bf(c.z); v[7] = f2bf(c.w);
  *(u16x8*)&WB[base] = v;
}

// =====================================================================
// Kernel A: MFMA bf16 projections -> bf16 projB [m][col][o]  (r12 form)
// =====================================================================
__global__ __launch_bounds__(512) void proj_kernel(const unsigned short* __restrict__ WB,
                                                   const unsigned short* __restrict__ XTB,
                                                   unsigned short* __restrict__ proj) {
  __shared__ __align__(16) unsigned short At[128 * 64];
  __shared__ __align__(16) unsigned short Bt[128 * 64];
  int m = blockIdx.z;
  int ctile = blockIdx.x * 128, otile = blockIdx.y * 128;
  const unsigned short* Wsrc = WB + (long)m * 409600L;
  unsigned short* out = proj + (long)m * NCOL * CCH;
  int tid = threadIdx.x;
  int w = tid >> 6, lane = tid & 63;
  int wr = w >> 2, wc = w & 3;
  int lr = lane & 31, ksel = lane >> 5;
  int sr = tid >> 2, sg = (tid & 3) * 2;

  f32x16 acc[2];
#pragma unroll
  for (int a = 0; a < 2; a++)
#pragma unroll
    for (int e = 0; e < 16; e++) acc[a][e] = 0.f;

  int bcol = ctile + sr;
  const unsigned short* asrc = Wsrc + (long)(otile + sr) * CCH + sg * 8;
  const unsigned short* bsrc = XTB + (long)bcol * CCH + sg * 8;

  u16x8 pa[2], pb[2];
#pragma unroll
  for (int gi = 0; gi < 2; gi++) {
    pa[gi] = *(const u16x8*)&asrc[gi * 8];
    if (bcol < NCOL) pb[gi] = *(const u16x8*)&bsrc[gi * 8];
    else { u16x8 z; for (int e = 0; e < 8; e++) z[e] = 0; pb[gi] = z; }
  }

  for (int kc = 0; kc < 10; kc++) {
    __syncthreads();
#pragma unroll
    for (int gi = 0; gi < 2; gi++) {
      int g = sg + gi;
      *(u16x8*)&At[sr * 64 + ((g ^ (sr & 7)) << 3)] = pa[gi];
      *(u16x8*)&Bt[sr * 64 + ((g ^ (sr & 7)) << 3)] = pb[gi];
    }
    if (kc < 9) {
      const unsigned short* an = asrc + (kc + 1) * 64;
      const unsigned short* bn = bsrc + (kc + 1) * 64;
#pragma unroll
      for (int gi = 0; gi < 2; gi++) {
        pa[gi] = *(const u16x8*)&an[gi * 8];
        if (bcol < NCOL) pb[gi] = *(const u16x8*)&bn[gi * 8];
      }
    }
    __syncthreads();
#pragma unroll
    for (int ks = 0; ks < 4; ks++) {
      int gk = ks * 2 + ksel;
      s16x8 bf1;
      {
        int R = wc * 32 + lr;
        bf1 = *(const s16x8*)&Bt[R * 64 + ((gk ^ (R & 7)) << 3)];
      }
#pragma unroll
      for (int a = 0; a < 2; a++) {
        int R = (wr + 2 * a) * 32 + lr;
        s16x8 af = *(const s16x8*)&At[R * 64 + ((gk ^ (R & 7)) << 3)];
        acc[a] = __builtin_amdgcn_mfma_f32_32x32x16_bf16(af, bf1, acc[a], 0, 0, 0);
      }
    }
  }

  int col = ctile + wc * 32 + lr;
  if (col < NCOL) {
#pragma unroll
    for (int a = 0; a < 2; a++) {
      int obase = otile + (wr + 2 * a) * 32 + 4 * ksel;
#pragma unroll
      for (int g2 = 0; g2 < 4; g2++) {
        u16x4 v;
        v.x = f2bf(acc[a][g2 * 4 + 0]);
        v.y = f2bf(acc[a][g2 * 4 + 1]);
        v.z = f2bf(acc[a][g2 * 4 + 2]);
        v.w = f2bf(acc[a][g2 * 4 + 3]);
        *(u16x4*)&out[(long)col * CCH + obase + g2 * 8] = v;
      }
    }
  }
}

// =====================================================================
// Kernel B: MFMA attention, templated on SIDE (r17-verified)
// =====================================================================
template<int SIDE>
__global__ __launch_bounds__(256) void attn_kernel(const unsigned short* __restrict__ proj,
                                                   const unsigned short* __restrict__ XTB,
                                                   unsigned short* __restrict__ feat,
                                                   int chunk_start) {
  int tid = threadIdx.x, wid = tid >> 6, lane = tid & 63;
  int lr = lane & 31, hf = lane >> 5;
  int rclamp = lr > 24 ? 24 : lr;
  int bid = blockIdx.x;
  int pw = bid / 5, grp = bid - pw * 5;
  int head = grp * 4 + wid;           // 0..19
  int lpi = pw / 5, way = pw - lpi * 5;
  int pair = chunk_start + lpi;
  int b = pair / 75;
  int qitem = 50 + pair;
  int qcol = qitem * PP;
  int sitem0 = b * 25 + way * 5;
  int ho = head * 32;
  const unsigned short* Qp = proj;
  const unsigned short* Kp = proj + (long)NCOL * CCH;
  const unsigned short* Vp = proj + 2L * NCOL * CCH;
  unsigned short* fb = feat + (long)pw * FEAT_PER_WAY_US + head * 250 * 32;

  auto ldfrag = [&](const unsigned short* src, int col0, int ks) -> s16x8 {
    return *(const s16x8*)&src[(long)(col0 + rclamp) * CCH + ho + ks * 16 + hf * 8];
  };
  auto ldvfrag = [&](int col0, int ks) -> s16x8 {
    const unsigned short* base = Vp + (long)(col0 + ks * 16 + hf * 8) * CCH + ho + lr;
    s16x8 f;
#pragma unroll
    for (int j = 0; j < 8; j++) f[j] = (short)base[(long)j * CCH];
    return f;
  };

  s16x8 fA0, fA1, fB0, fB1, fV0, fV1;
  float scv[16];
  if (SIDE == 0) {               // sbq: Q = query item fixed
    fB0 = ldfrag(Qp, qcol, 0); fB1 = ldfrag(Qp, qcol, 1);
  } else {                       // qbs: K/V = query item fixed; shortcut fixed too
    fA0 = ldfrag(Kp, qcol, 0); fA1 = ldfrag(Kp, qcol, 1);
    fV0 = ldvfrag(qcol, 0);    fV1 = ldvfrag(qcol, 1);
#pragma unroll
    for (int rg = 0; rg < 16; rg++) {
      int q = (rg & 3) + 8 * (rg >> 2) + 4 * hf;
      int qc = q > 24 ? 24 : q;
      scv[rg] = bf2f(XTB[(long)(qcol + qc) * CCH + ho + lr]);
    }
  }

#pragma unroll
  for (int shot = 0; shot < 5; shot++) {
    int scol = (sitem0 + shot) * PP;
    s16x8 A0, A1, B0, B1, V0, V1;
    if (SIDE == 0) {
      A0 = ldfrag(Kp, scol, 0); A1 = ldfrag(Kp, scol, 1);
      B0 = fB0; B1 = fB1;
      V0 = ldvfrag(scol, 0);    V1 = ldvfrag(scol, 1);
    } else {
      A0 = fA0; A1 = fA1;
      B0 = ldfrag(Qp, scol, 0); B1 = ldfrag(Qp, scol, 1);
      V0 = fV0; V1 = fV1;
    }
    // S^T = K·Q^T : D[m][q], q = lr
    f32x16 s;
#pragma unroll
    for (int e = 0; e < 16; e++) s[e] = 0.f;
    s = __builtin_amdgcn_mfma_f32_32x32x16_bf16(A0, B0, s, 0, 0, 0);
    s = __builtin_amdgcn_mfma_f32_32x32x16_bf16(A1, B1, s, 0, 0, 0);
    // softmax: tree max (unmasked; m>=25 replicates valid row 24)
    float t8[8];
#pragma unroll
    for (int i = 0; i < 8; i++) t8[i] = fmaxf(s[i], s[i + 8]);
#pragma unroll
    for (int i = 0; i < 4; i++) t8[i] = fmaxf(t8[i], t8[i + 4]);
    float mx = fmaxf(fmaxf(t8[0], t8[1]), fmaxf(t8[2], t8[3]));
    mx = fmaxf(mx, __shfl_xor(mx, 32));
    float pv[16];
#pragma unroll
    for (int rg = 0; rg < 16; rg++) pv[rg] = __expf((s[rg] - mx) * SCALE_INV);
    pv[13] = 0.f; pv[14] = 0.f; pv[15] = 0.f;   // m=25,26,27 / 29,30,31
    if (hf) pv[12] = 0.f;                        // m=28
    float s8[8];
#pragma unroll
    for (int i = 0; i < 8; i++) s8[i] = pv[i] + pv[i + 8];
#pragma unroll
    for (int i = 0; i < 4; i++) s8[i] = s8[i] + s8[i + 4];
    float sum = (s8[0] + s8[1]) + (s8[2] + s8[3]);
    sum += __shfl_xor(sum, 32);
    float rinv = 1.f / sum;
    // P A-frags: cvt_pk then permlane32_swap half-exchange
    union { unsigned u[4]; s16x8 v; } P0u, P1u;
    {
      unsigned a0 = cvtpk(pv[0], pv[1]),  a1 = cvtpk(pv[2], pv[3]);
      unsigned a2 = cvtpk(pv[4], pv[5]),  a3 = cvtpk(pv[6], pv[7]);
      plswap(a2, a0);
      plswap(a3, a1);
      P0u.u[0] = a0; P0u.u[1] = a1; P0u.u[2] = a2; P0u.u[3] = a3;
      unsigned b0 = cvtpk(pv[8], pv[9]),   b1 = cvtpk(pv[10], pv[11]);
      unsigned b2 = cvtpk(pv[12], pv[13]), b3 = cvtpk(pv[14], pv[15]);
      plswap(b2, b0);
      plswap(b3, b1);
      P1u.u[0] = b0; P1u.u[1] = b1; P1u.u[2] = b2; P1u.u[3] = b3;
    }
    // O = P·V (unnormalized)
    f32x16 o;
#pragma unroll
    for (int e = 0; e < 16; e++) o[e] = 0.f;
    o = __builtin_amdgcn_mfma_f32_32x32x16_bf16(P0u.v, V0, o, 0, 0, 0);
    o = __builtin_amdgcn_mfma_f32_32x32x16_bf16(P1u.v, V1, o, 0, 0, 0);
    // epilogue: o*rinv + shortcut, paired cvt_pk, bf16 store
    unsigned short* frow = fb + (long)((SIDE ? 125 : 0) + shot * 25) * 32;
    const unsigned short* scb = XTB + (long)(scol + 4 * hf) * CCH + ho + lr;
#pragma unroll
    for (int i = 0; i < 8; i++) {
      int rg0 = 2 * i, rg1 = rg0 + 1;
      int qoff = (rg0 & 3) + 8 * (rg0 >> 2);
      int q0 = qoff + 4 * hf, q1 = q0 + 1;
      float sc0, sc1;
      if (SIDE) { sc0 = scv[rg0]; sc1 = scv[rg1]; }
      else {
        sc0 = bf2f(scb[(long)qoff * CCH]);
        sc1 = bf2f(scb[(long)(qoff + 1) * CCH]);
      }
      unsigned u = cvtpk(fmaf(o[rg0], rinv, sc0), fmaf(o[rg1], rinv, sc1));
      if (q0 < 25) frow[q0 * 32 + lr] = (unsigned short)u;
      if (q1 < 25) frow[q1 * 32 + lr] = (unsigned short)(u >> 16);
    }
  }
}

// =====================================================================
// Kernel C: MFMA bf16 Gram, SYMMETRIC: 640 thr / 10 waves, one 2x2
// supertile per wave over the upper triangle of the 4x4 supertile grid.
// Off-diagonal elements weighted x2; ti>tj subtiles skipped in epilogue.
// (r18-measured best-total configuration)
// =====================================================================
__global__ __launch_bounds__(640) void gram_kernel(const unsigned short* __restrict__ feat,
                                                   const unsigned short* __restrict__ ones,
                                                   float* __restrict__ mmd,
                                                   int chunk_start) {
  __shared__ __align__(16) unsigned short tile[2][16384];
  __shared__ float sums[256], nrmsq[256], meanv[256], nrmv[256];
  __shared__ float red[30];
  int bid = blockIdx.x;
  const unsigned short* fb = feat + (long)bid * FEAT_PER_WAY_US;
  int tid = threadIdx.x;
  int w = tid >> 6, lane = tid & 63;
  int lr = lane & 31, ksel = lane >> 5;

  // supertile (sti, stj) for wave w over upper triangle of 4x4 grid
  int sti, stj;
  if (w < 4)      { sti = 0; stj = w; }
  else if (w < 7) { sti = 1; stj = w - 3; }
  else if (w < 9) { sti = 2; stj = w - 5; }
  else            { sti = 3; stj = 3; }

  // staging: slots s = tid + i*640 (2048 total), pre-swizzled sources
  const unsigned short* srcp[4];
  long stepv[4];
#pragma unroll
  for (int i = 0; i < 4; i++) {
    int s = tid + i * 640;
    if (s < 2048) {
      int row = s >> 3, gs = s & 7, g = gs ^ (row & 7);
      if (row < 250) {
        srcp[i] = fb + (long)((g >> 2) * 250 + row) * 32 + (g & 3) * 8;
        stepv[i] = 16000;
      } else {
        srcp[i] = ones + (row - 250) * 64 + g * 8;
        stepv[i] = 0;
      }
    }
  }

  f32x16 acc[2][2];
#pragma unroll
  for (int a = 0; a < 2; a++)
#pragma unroll
    for (int b2 = 0; b2 < 2; b2++)
#pragma unroll
      for (int e = 0; e < 16; e++) acc[a][b2][e] = 0.f;

  // prologue: stage kc=0 into buf 0
#pragma unroll
  for (int i = 0; i < 4; i++) {
    int s = tid + i * 640;
    if (s < 2048)
      __builtin_amdgcn_global_load_lds((glb_u32*)srcp[i],
                                       (lds_u32*)&tile[0][s * 8], 16, 0, 0);
  }
  __syncthreads();

  for (int kc = 0; kc < 10; kc++) {
    int cur = kc & 1;
    if (kc < 9) {
#pragma unroll
      for (int i = 0; i < 4; i++) {
        int s = tid + i * 640;
        if (s < 2048)
          __builtin_amdgcn_global_load_lds((glb_u32*)(srcp[i] + (long)(kc + 1) * stepv[i]),
                                           (lds_u32*)&tile[cur ^ 1][s * 8], 16, 0, 0);
      }
    }
    const unsigned short* tb = tile[cur];
#pragma unroll
    for (int ks = 0; ks < 4; ks++) {
      int gk = ks * 2 + ksel;
      s16x8 af[2], bfv[2];
#pragma unroll
      for (int a = 0; a < 2; a++) {
        int R = (sti * 2 + a) * 32 + lr;
        af[a] = *(const s16x8*)&tb[R * 64 + ((gk ^ (R & 7)) << 3)];
      }
#pragma unroll
      for (int b2 = 0; b2 < 2; b2++) {
        int R = (stj * 2 + b2) * 32 + lr;
        bfv[b2] = *(const s16x8*)&tb[R * 64 + ((gk ^ (R & 7)) << 3)];
      }
#pragma unroll
      for (int a = 0; a < 2; a++)
#pragma unroll
        for (int b2 = 0; b2 < 2; b2++)
          acc[a][b2] = __builtin_amdgcn_mfma_f32_32x32x16_bf16(af[a], bfv[b2], acc[a][b2], 0, 0, 0);
    }
    __syncthreads();
  }

  // ---- harvest row sums (col 250) and squared norms (diagonal) ----
#pragma unroll
  for (int a = 0; a < 2; a++) {
    int ti = sti * 2 + a;
#pragma unroll
    for (int b2 = 0; b2 < 2; b2++) {
      int tj = stj * 2 + b2;
      int col = tj * 32 + lr;
      if (col == 250) {
#pragma unroll
        for (int rg = 0; rg < 16; rg++) {
          int row = ti * 32 + (rg & 3) + 8 * (rg >> 2) + 4 * ksel;
          if (row < 250) sums[row] = acc[a][b2][rg];
        }
      }
      if (ti == tj) {
#pragma unroll
        for (int rg = 0; rg < 16; rg++) {
          int row = ti * 32 + (rg & 3) + 8 * (rg >> 2) + 4 * ksel;
          if (row == col && row < 250) nrmsq[row] = acc[a][b2][rg];
        }
      }
    }
  }
  __syncthreads();
  if (tid < 250) {
    float s0 = sums[tid];
    float m = s0 * (1.f / 640.f);
    meanv[tid] = m;
    nrmv[tid] = nrmsq[tid] - s0 * m;
  }
  __syncthreads();

  // ---- epilogue: d2 -> 5-term kernel; weight 2 for ti<tj, skip ti>tj ----
  float s_ss = 0.f, s_qq = 0.f, s_x = 0.f;
#pragma unroll
  for (int a = 0; a < 2; a++) {
    int ti = sti * 2 + a;
#pragma unroll
    for (int b2 = 0; b2 < 2; b2++) {
      int tj = stj * 2 + b2;
      if (ti > tj) continue;               // transpose counted by (tj,ti) weight
      float w2 = (ti < tj) ? 2.f : 1.f;
      int col = tj * 32 + lr;
#pragma unroll
      for (int rg = 0; rg < 16; rg++) {
        int row = ti * 32 + (rg & 3) + 8 * (rg >> 2) + 4 * ksel;
        if (row < 250 && col < 250) {
          float d2 = nrmv[row] + nrmv[col] - 2.f * acc[a][b2][rg]
                   + 1280.f * meanv[row] * meanv[col];
          d2 = fmaxf(d2, 0.f);
          float e = __expf(-0.125f * d2);
          float e2 = e * e, e4 = e2 * e2, e8 = e4 * e4, e16 = e8 * e8;
          float kv = w2 * (e + e2 + e4 + e8 + e16);
          bool rs = row < 125, cs = col < 125;
          if (rs && cs)        { if (row != col) s_ss += kv; }
          else if (!rs && !cs) { if (row != col) s_qq += kv; }
          else                 s_x += kv;   // counts Kqs + Ksq = 2*tot(Kqs)
        }
      }
    }
  }
#pragma unroll
  for (int off = 32; off; off >>= 1) {
    s_ss += __shfl_xor(s_ss, off);
    s_qq += __shfl_xor(s_qq, off);
    s_x  += __shfl_xor(s_x, off);
  }
  if (lane == 0) { red[w * 3] = s_ss; red[w * 3 + 1] = s_qq; red[w * 3 + 2] = s_x; }
  __syncthreads();
  if (tid == 0) {
    float a = 0.f, b2 = 0.f, c = 0.f;
    for (int i = 0; i < 10; i++) { a += red[i * 3]; b2 += red[i * 3 + 1]; c += red[i * 3 + 2]; }
    mmd[(long)chunk_start * 5 + bid] = a * (1.f / 15500.f) + b2 * (1.f / 15500.f) - c * (1.f / 15625.f);
  }
}

// =====================================================================
// Kernel D: log-softmax + NLL mean
// =====================================================================
__global__ __launch_bounds__(256) void loss_kernel(const float* __restrict__ mmd,
                                                   const int* __restrict__ qy,
                                                   float* __restrict__ out) {
  __shared__ float red[256];
  int tid = threadIdx.x;
  float val = 0.f;
  if (tid < 150) {
    float l[5];
    float mx = -1e30f;
#pragma unroll
    for (int w = 0; w < 5; w++) {
      l[w] = -mmd[tid * 5 + w] * (1.0f / 12.5f);
      mx = fmaxf(mx, l[w]);
    }
    float sum = 0.f;
#pragma unroll
    for (int w = 0; w < 5; w++) sum += __expf(l[w] - mx);
    float lse = mx + logf(sum);
    int y = qy[tid];
    val = -(l[y] - lse);
  }
  red[tid] = val;
  __syncthreads();
  for (int s = 128; s > 0; s >>= 1) {
    if (tid < s) red[tid] += red[tid + s];
    __syncthreads();
  }
  if (tid == 0) out[0] = red[0] * (1.0f / 150.0f);
}

// =====================================================================
extern "C" void kernel_launch(void* const* d_in, const int* in_sizes, int n_in,
                              void* d_out, int out_size, void* d_ws, size_t ws_size,
                              hipStream_t stream) {
  (void)in_sizes; (void)n_in; (void)out_size;
  const float* sup = (const float*)d_in[0];
  const float* qry = (const float*)d_in[2];
  const int* qy = (const int*)d_in[3];
  const float* Wq = (const float*)d_in[4];
  const float* Wk = (const float*)d_in[5];
  const float* Wv = (const float*)d_in[6];
  float* ws = (float*)d_ws;
  unsigned short* XTB = (unsigned short*)(ws + XTB_OFF);
  unsigned short* WB = (unsigned short*)(ws + WB_OFF);
  unsigned short* projB = (unsigned short*)(ws + PROJB_OFF);
  float* mmd = ws + MMD_OFF;
  unsigned short* ones = (unsigned short*)(ws + ONES_OFF);
  unsigned short* feat = (unsigned short*)(ws + FEAT_OFF);
  float* out = (float*)d_out;

  long wsf = (long)(ws_size / 4);
  long avail_us = (wsf - FEAT_OFF) * 2;
  long chunkL = avail_us / FEAT_PER_PAIR_US;
  int chunk = (chunkL > 150) ? 150 : (chunkL < 1 ? 1 : (int)chunkL);

  hipLaunchKernelGGL(t_kernel, dim3(200), dim3(256), 0, stream, sup, qry, XTB);
  hipLaunchKernelGGL(w_kernel, dim3(600), dim3(256), 0, stream, Wq, Wk, Wv, WB, ones);
  hipLaunchKernelGGL(proj_kernel, dim3(40, 5, 3), dim3(512), 0, stream, WB, XTB, projB);
  for (int c0 = 0; c0 < 150; c0 += chunk) {
    int cp = (150 - c0 < chunk) ? (150 - c0) : chunk;
    hipLaunchKernelGGL((attn_kernel<0>), dim3(cp * 25), dim3(256), 0, stream, projB, XTB, feat, c0);
    hipLaunchKernelGGL((attn_kernel<1>), dim3(cp * 25), dim3(256), 0, stream, projB, XTB, feat, c0);
    hipLaunchKernelGGL(gram_kernel, dim3(cp * 5), dim3(640), 0, stream, feat, ones, mmd, c0);
  }
  hipLaunchKernelGGL(loss_kernel, dim3(1), dim3(256), 0, stream, mmd, qy, out);
}